// Round 5
// baseline (434.215 us; speedup 1.0000x reference)
//
#include <hip/hip_runtime.h>
#include <hip/hip_bf16.h>

#define NC 80
#define NK 51
#define REG_MAX 16
#define MAX_DET 100
#define A_TOT 8400
#define BS 16

// out layout (float32): num[16] | boxes[16*100*4] | scores[16*100] | classes[16*100] | kpts[16*100*17*3]
#define OUT_NUM 0
#define OUT_BOX 16
#define OUT_SCORE (16 + 16*MAX_DET*4)
#define OUT_CLASS (OUT_SCORE + 16*MAX_DET)
#define OUT_KPT (OUT_CLASS + 16*MAX_DET)

static __device__ __forceinline__ unsigned long long mk_key(unsigned u, int a) {
    return ((unsigned long long)u << 32) | (unsigned)(0x7FFFFFFF - a);
}

// -------- Kernel 1 v6: per-lane register-tile GEMM --------
// v1/v2/v5 all lost to broadcast-style weight distribution (uniform
// ds_read / readlane deliver 4 floats per ~10cy). Canonical fix: each
// lane owns a 10oc x 8anchor register tile; weights are PER-LANE-DISTINCT
// ds_read_b128 (256 floats/instr across the wave). Per c4 group/wave:
// 10 ds_read_b128 (120 cy) + 8 global float4 + 320 FMA (640 cy) ->
// VALU-bound (LDS duty 0.75 per CU at 4 waves). Weight chunks double-
// buffered: global->regs issued BEFORE compute, ds_write+1 barrier after
// (latency hidden under ~5120 cy compute). Wave argmax-self-sufficient:
// cross-og reduce via 3 shfl_xor rounds, ties -> lower og (first-max).
// Per (oc,anchor) chain: bias then ascending channels - bit-identical.
// LDS row stride 36 floats: og stride 1440 B -> bank-quads {0,8,16,24}x2
// -> 2-way (free, m136).
template<int C, int A>
static __device__ __forceinline__ void score_tile(
    const float* __restrict__ x, const float* __restrict__ w,
    const float* __restrict__ bias,
    int b, int a0, int a_off,
    float* __restrict__ max_s, int* __restrict__ cls_id,
    float* __restrict__ wsh)        // [2][80*36]
{
    int t = threadIdx.x;
    int lane = t & 63;
    int wv = t >> 6;
    int og = lane >> 3;             // 8 oc-groups of 10
    int slot = lane & 7;            // 8 anchor-slots of 8
    int oc0 = og * 10;

    int aa = a0 + wv * 64 + slot * 8;
    if (aa > A - 8) aa = A - 8;     // A%8==0 -> clamped lanes' nominal ga all >= A (writes guarded)
    const float* xb = x + (long)b * C * A + aa;

    float acc[10][8];
#pragma unroll
    for (int j = 0; j < 10; ++j) {
        float bv = bias[oc0 + j];
#pragma unroll
        for (int q = 0; q < 8; ++q) acc[j][q] = bv;
    }

    constexpr int NCH = C >> 5;

    // staging registers: 640 float4 per chunk / 256 threads -> up to 3 each
    float4 st0, st1, st2;
    int i0 = t, i1 = t + 256, i2 = t + 512;
    int oc_0 = i0 >> 3, q_0 = i0 & 7;
    int oc_1 = i1 >> 3, q_1 = i1 & 7;
    int oc_2 = i2 >> 3, q_2 = i2 & 7;
    bool v2ld = (i2 < 640);

    // prologue: stage chunk 0
    st0 = *(const float4*)(w + oc_0 * C + q_0 * 4);
    st1 = *(const float4*)(w + oc_1 * C + q_1 * 4);
    if (v2ld) st2 = *(const float4*)(w + oc_2 * C + q_2 * 4);
    *(float4*)(&wsh[oc_0 * 36 + q_0 * 4]) = st0;
    *(float4*)(&wsh[oc_1 * 36 + q_1 * 4]) = st1;
    if (v2ld) *(float4*)(&wsh[oc_2 * 36 + q_2 * 4]) = st2;
    __syncthreads();

    for (int kc = 0; kc < NCH; ++kc) {
        int p = kc & 1;
        int cbase = kc * 32;

        if (kc + 1 < NCH) {         // issue next chunk's loads (latency hides under compute)
            const float* wn = w + (cbase + 32);
            st0 = *(const float4*)(wn + oc_0 * C + q_0 * 4);
            st1 = *(const float4*)(wn + oc_1 * C + q_1 * 4);
            if (v2ld) st2 = *(const float4*)(wn + oc_2 * C + q_2 * 4);
        }

        const float* wp = wsh + p * 2880 + oc0 * 36;
#pragma unroll 2
        for (int c4 = 0; c4 < 32; c4 += 4) {
            const float* fp = xb + (long)(cbase + c4) * A;
            float4 fA[4], fB[4];
#pragma unroll
            for (int cc = 0; cc < 4; ++cc) {
                fA[cc] = *(const float4*)(fp + (long)cc * A);
                fB[cc] = *(const float4*)(fp + (long)cc * A + 4);
            }
#pragma unroll
            for (int j = 0; j < 10; ++j) {
                float4 w4 = *(const float4*)(wp + j * 36 + c4);   // per-lane-distinct b128
                // ascending-channel chain per (oc, anchor) - bit-identical
                acc[j][0] = fmaf(w4.x, fA[0].x, acc[j][0]);
                acc[j][0] = fmaf(w4.y, fA[1].x, acc[j][0]);
                acc[j][0] = fmaf(w4.z, fA[2].x, acc[j][0]);
                acc[j][0] = fmaf(w4.w, fA[3].x, acc[j][0]);
                acc[j][1] = fmaf(w4.x, fA[0].y, acc[j][1]);
                acc[j][1] = fmaf(w4.y, fA[1].y, acc[j][1]);
                acc[j][1] = fmaf(w4.z, fA[2].y, acc[j][1]);
                acc[j][1] = fmaf(w4.w, fA[3].y, acc[j][1]);
                acc[j][2] = fmaf(w4.x, fA[0].z, acc[j][2]);
                acc[j][2] = fmaf(w4.y, fA[1].z, acc[j][2]);
                acc[j][2] = fmaf(w4.z, fA[2].z, acc[j][2]);
                acc[j][2] = fmaf(w4.w, fA[3].z, acc[j][2]);
                acc[j][3] = fmaf(w4.x, fA[0].w, acc[j][3]);
                acc[j][3] = fmaf(w4.y, fA[1].w, acc[j][3]);
                acc[j][3] = fmaf(w4.z, fA[2].w, acc[j][3]);
                acc[j][3] = fmaf(w4.w, fA[3].w, acc[j][3]);
                acc[j][4] = fmaf(w4.x, fB[0].x, acc[j][4]);
                acc[j][4] = fmaf(w4.y, fB[1].x, acc[j][4]);
                acc[j][4] = fmaf(w4.z, fB[2].x, acc[j][4]);
                acc[j][4] = fmaf(w4.w, fB[3].x, acc[j][4]);
                acc[j][5] = fmaf(w4.x, fB[0].y, acc[j][5]);
                acc[j][5] = fmaf(w4.y, fB[1].y, acc[j][5]);
                acc[j][5] = fmaf(w4.z, fB[2].y, acc[j][5]);
                acc[j][5] = fmaf(w4.w, fB[3].y, acc[j][5]);
                acc[j][6] = fmaf(w4.x, fB[0].z, acc[j][6]);
                acc[j][6] = fmaf(w4.y, fB[1].z, acc[j][6]);
                acc[j][6] = fmaf(w4.z, fB[2].z, acc[j][6]);
                acc[j][6] = fmaf(w4.w, fB[3].z, acc[j][6]);
                acc[j][7] = fmaf(w4.x, fB[0].w, acc[j][7]);
                acc[j][7] = fmaf(w4.y, fB[1].w, acc[j][7]);
                acc[j][7] = fmaf(w4.z, fB[2].w, acc[j][7]);
                acc[j][7] = fmaf(w4.w, fB[3].w, acc[j][7]);
            }
        }

        if (kc + 1 < NCH) {         // write next chunk into other buffer; one barrier/chunk
            float* wd = wsh + (p ^ 1) * 2880;
            *(float4*)(&wd[oc_0 * 36 + q_0 * 4]) = st0;
            *(float4*)(&wd[oc_1 * 36 + q_1 * 4]) = st1;
            if (v2ld) *(float4*)(&wd[oc_2 * 36 + q_2 * 4]) = st2;
            __syncthreads();
        }
    }

    // per-lane argmax over own 10 ocs (first-max: ascending j, strict >)
    float m[8]; int id[8];
#pragma unroll
    for (int q = 0; q < 8; ++q) {
        float mm = acc[0][q]; int mi = 0;
#pragma unroll
        for (int j = 1; j < 10; ++j)
            if (acc[j][q] > mm) { mm = acc[j][q]; mi = j; }
        m[q] = mm; id[q] = oc0 + mi;
    }

    // cross-og reduce via shfl_xor; ties -> lower og (first-max over oc)
#pragma unroll
    for (int mask = 8; mask <= 32; mask <<= 1) {
        bool other_first = (lane & mask) != 0;   // partner lane is lower -> lower oc range
#pragma unroll
        for (int q = 0; q < 8; ++q) {
            float om = __shfl_xor(m[q], mask, 64);
            int   oi = __shfl_xor(id[q], mask, 64);
            bool take = other_first ? (om >= m[q]) : (om > m[q]);
            if (take) { m[q] = om; id[q] = oi; }
        }
    }

    if (og == 0) {                  // lanes 0..7, slot == lane
        int base = a0 + wv * 64 + slot * 8;
#pragma unroll
        for (int q = 0; q < 8; ++q) {
            int ga = base + q;      // nominal anchor (clamped lanes: ga >= A, skipped)
            if (ga < A) {
                max_s[b * A_TOT + a_off + ga] = 1.0f / (1.0f + expf(-m[q]));
                cls_id[b * A_TOT + a_off + ga] = id[q];
            }
        }
    }
}

__global__ __launch_bounds__(256, 2) void scores_fused(
    const float* __restrict__ x0, const float* __restrict__ x1, const float* __restrict__ x2,
    const float* __restrict__ w0, const float* __restrict__ w1, const float* __restrict__ w2,
    const float* __restrict__ bias0, const float* __restrict__ bias1, const float* __restrict__ bias2,
    float* __restrict__ max_s,       // [BS][A_TOT]
    int* __restrict__ cls_id)        // [BS][A_TOT]
{
    __shared__ float wsh[2 * 80 * 36];   // 23 KB double-buffered weight chunk (padded rows)

    int bid = blockIdx.x;
    if (bid < 32) {                  // L2 first: 16 b x 2 tiles of 256 anchors
        int b = bid >> 1, tile = bid & 1;
        score_tile<512, 400>(x2, w2, bias2, b, tile * 256, 8000, max_s, cls_id, wsh);
    } else if (bid < 144) {          // L1: 16 b x 7 tiles of 256 (ragged, clamped)
        int r = bid - 32;
        int b = r / 7, tile = r - b * 7;
        score_tile<256, 1600>(x1, w1, bias1, b, tile * 256, 6400, max_s, cls_id, wsh);
    } else {                         // L0: 16 b x 25 tiles of 256
        int r = bid - 144;
        int b = r / 25, tile = r - b * 25;
        score_tile<128, 6400>(x0, w0, bias0, b, tile * 256, 0, max_s, cls_id, wsh);
    }
}

// -------- Kernel 2: exact top-100 per batch via radix select (unchanged) --------
__global__ __launch_bounds__(1024) void topk_kernel(
    const float* __restrict__ max_s, // [BS][A_TOT]
    const int* __restrict__ cls_id,  // [BS][A_TOT]
    float* __restrict__ out,
    int* __restrict__ top_idx)       // [BS][MAX_DET]
{
    int b = blockIdx.x;
    int t = threadIdx.x;
    int wv = t >> 6;

    __shared__ unsigned hist[16 * 256];          // per-wave histograms, 16 KB
    __shared__ unsigned suffix[256];
    __shared__ int tieIdx[A_TOT];                // 33.6 KB
    __shared__ unsigned long long highKeys[128];
    __shared__ unsigned long long finalKeys[128];
    __shared__ int wmin[16];
    __shared__ unsigned s_prefix;
    __shared__ int s_k, s_selD, s_nHigh, s_nTie, s_cnt, s_bcast;

    unsigned u[9];
    bool val[9];
#pragma unroll
    for (int i = 0; i < 9; ++i) {
        int a = t + i * 1024;
        val[i] = (a < A_TOT);
        u[i] = val[i] ? __float_as_uint(max_s[b * A_TOT + a]) : 0u;
    }

    if (t == 0) { s_prefix = 0; s_k = MAX_DET; s_nHigh = 0; s_nTie = 0; s_cnt = 0; }

    for (int pass = 0; pass < 4; ++pass) {
#pragma unroll
        for (int j = 0; j < 4; ++j) hist[t + j * 1024] = 0;
        if (t == 0) s_selD = 0;
        __syncthreads();

        unsigned pre = s_prefix;
        int k = s_k;
        int shHi = 32 - 8 * pass;
        int shD = 24 - 8 * pass;
#pragma unroll
        for (int i = 0; i < 9; ++i) {
            if (val[i]) {
                bool cand = (pass == 0) ? true : ((u[i] >> shHi) == pre);
                if (cand)
                    atomicAdd(&hist[(wv << 8) + ((u[i] >> shD) & 0xFF)], 1u);
            }
        }
        __syncthreads();

        if (t < 256) {
            unsigned s = 0;
#pragma unroll
            for (int w = 0; w < 16; ++w) s += hist[(w << 8) + t];
            suffix[t] = s;
        }
        __syncthreads();
        for (int off = 1; off < 256; off <<= 1) {
            unsigned v = 0;
            if (t < 256) v = suffix[t] + ((t + off < 256) ? suffix[t + off] : 0u);
            __syncthreads();
            if (t < 256) suffix[t] = v;
            __syncthreads();
        }
        if (t < 256 && suffix[t] >= (unsigned)k) atomicMax(&s_selD, t);
        __syncthreads();
        if (t == 0) {
            int d = s_selD;
            s_k = k - ((d < 255) ? (int)suffix[d + 1] : 0);
            s_prefix = (pre << 8) | (unsigned)d;
        }
        __syncthreads();
    }

    unsigned cut = s_prefix;
    int r = s_k;

#pragma unroll
    for (int i = 0; i < 9; ++i) {
        if (val[i]) {
            int a = t + i * 1024;
            if (u[i] > cut) {
                int p = atomicAdd(&s_nHigh, 1);
                highKeys[p] = mk_key(u[i], a);
            } else if (u[i] == cut) {
                int p = atomicAdd(&s_nTie, 1);
                tieIdx[p] = a;
            }
        }
    }
    __syncthreads();
    int m = s_nHigh;
    int nt = s_nTie;

    if (t < 128) finalKeys[t] = 0ull;
    __syncthreads();
    if (t < m) finalKeys[t] = highKeys[t];

    if (nt == r) {
        if (t < nt) finalKeys[m + t] = mk_key(cut, tieIdx[t]);
        __syncthreads();
    } else {
        __syncthreads();
        for (int j = 0; j < r; ++j) {
            int mn = 0x7FFFFFFF;
            for (int p = t; p < nt; p += 1024) mn = min(mn, tieIdx[p]);
            for (int off = 32; off > 0; off >>= 1) mn = min(mn, __shfl_down(mn, off, 64));
            if ((t & 63) == 0) wmin[wv] = mn;
            __syncthreads();
            if (t == 0) {
                int v = wmin[0];
#pragma unroll
                for (int w = 1; w < 16; ++w) v = min(v, wmin[w]);
                s_bcast = v;
                finalKeys[m + j] = mk_key(cut, v);
            }
            __syncthreads();
            int v = s_bcast;
            for (int p = t; p < nt; p += 1024)
                if (tieIdx[p] == v) tieIdx[p] = 0x7FFFFFFF;
            __syncthreads();
        }
    }

    for (int ksz = 2; ksz <= 128; ksz <<= 1) {
        for (int j = ksz >> 1; j > 0; j >>= 1) {
            if (t < 128) {
                int ixj = t ^ j;
                if (ixj > t) {
                    bool desc = ((t & ksz) == 0);
                    unsigned long long x = finalKeys[t], y = finalKeys[ixj];
                    bool sw = desc ? (x < y) : (x > y);
                    if (sw) { finalKeys[t] = y; finalKeys[ixj] = x; }
                }
            }
            __syncthreads();
        }
    }

    if (t < MAX_DET) {
        unsigned long long kk = finalKeys[t];
        float sc = __uint_as_float((unsigned)(kk >> 32));
        int a = 0x7FFFFFFF - (int)(kk & 0xFFFFFFFFull);
        out[OUT_SCORE + b * MAX_DET + t] = sc;
        out[OUT_CLASS + b * MAX_DET + t] = (float)cls_id[b * A_TOT + a];
        top_idx[b * MAX_DET + t] = a;
        if (sc > 0.25f) atomicAdd(&s_cnt, 1);
    }
    __syncthreads();
    if (t == 0) out[OUT_NUM + b] = (float)s_cnt;
}

// -------- Kernel 3: decode box + kpts for selected anchors only (unchanged) --------
__global__ __launch_bounds__(128) void decode_kernel(
    const float* __restrict__ x0, const float* __restrict__ x1, const float* __restrict__ x2,
    const float* __restrict__ w2_0, const float* __restrict__ b2_0,
    const float* __restrict__ w2_1, const float* __restrict__ b2_1,
    const float* __restrict__ w2_2, const float* __restrict__ b2_2,
    const float* __restrict__ w4_0, const float* __restrict__ b4_0,
    const float* __restrict__ w4_1, const float* __restrict__ b4_1,
    const float* __restrict__ w4_2, const float* __restrict__ b4_2,
    const int* __restrict__ top_idx,
    float* __restrict__ out)
{
    int b = blockIdx.y;
    int k = blockIdx.x;
    int a = top_idx[b * MAX_DET + k];

    const float* x; const float* w2; const float* bb2; const float* w4; const float* bb4;
    int C, A, W, a_local; float stride;
    if (a < 6400)      { x = x0; C = 128; A = 6400; W = 80; stride = 8.0f;  a_local = a;        w2 = w2_0; bb2 = b2_0; w4 = w4_0; bb4 = b4_0; }
    else if (a < 8000) { x = x1; C = 256; A = 1600; W = 40; stride = 16.0f; a_local = a - 6400; w2 = w2_1; bb2 = b2_1; w4 = w4_1; bb4 = b4_1; }
    else               { x = x2; C = 512; A = 400;  W = 20; stride = 32.0f; a_local = a - 8000; w2 = w2_2; bb2 = b2_2; w4 = w4_2; bb4 = b4_2; }

    __shared__ float fs[512];
    __shared__ float logits[64];
    __shared__ float kraw[NK];
    __shared__ float dist[4];

    int t = threadIdx.x;
    for (int c = t; c < C; c += 128)
        fs[c] = x[((long)b * C + c) * A + a_local];
    __syncthreads();

    if (t < 64 + NK) {
        const float* wrow; float acc;
        if (t < 64) { wrow = w2 + t * C; acc = bb2[t]; }
        else        { wrow = w4 + (t - 64) * C; acc = bb4[t - 64]; }
        for (int c = 0; c < C; ++c) acc = fmaf(wrow[c], fs[c], acc);
        if (t < 64) logits[t] = acc;
        else        kraw[t - 64] = acc;
    }
    __syncthreads();

    if (t < 4) {
        float mx = logits[t * 16];
#pragma unroll
        for (int r = 1; r < 16; ++r) mx = fmaxf(mx, logits[t * 16 + r]);
        float se = 0.0f, sw = 0.0f;
#pragma unroll
        for (int r = 0; r < 16; ++r) {
            float e = expf(logits[t * 16 + r] - mx);
            se += e; sw += e * (float)r;
        }
        dist[t] = sw / se;
    }
    __syncthreads();

    float ax = (float)(a_local % W) + 0.5f;
    float ay = (float)(a_local / W) + 0.5f;

    if (t == 0) {
        float x1c = ax - dist[0], y1c = ay - dist[1];
        float x2c = ax + dist[2], y2c = ay + dist[3];
        float* ob = out + OUT_BOX + ((long)b * MAX_DET + k) * 4;
        ob[0] = (x1c + x2c) * 0.5f * stride;
        ob[1] = (y1c + y2c) * 0.5f * stride;
        ob[2] = (x2c - x1c) * stride;
        ob[3] = (y2c - y1c) * stride;
    }
    if (t < 17) {
        float vx = kraw[t * 3], vy = kraw[t * 3 + 1], vv = kraw[t * 3 + 2];
        float gx = ax - 0.5f, gy = ay - 0.5f;
        float* ok = out + OUT_KPT + (((long)b * MAX_DET + k) * 17 + t) * 3;
        ok[0] = (vx * 2.0f + gx) * stride;
        ok[1] = (vy * 2.0f + gy) * stride;
        ok[2] = 1.0f / (1.0f + expf(-vv));
    }
}

extern "C" void kernel_launch(void* const* d_in, const int* in_sizes, int n_in,
                              void* d_out, int out_size, void* d_ws, size_t ws_size,
                              hipStream_t stream) {
    const float* x0 = (const float*)d_in[0];
    const float* x1 = (const float*)d_in[1];
    const float* x2 = (const float*)d_in[2];
    const float* w2[3] = {(const float*)d_in[3], (const float*)d_in[5], (const float*)d_in[7]};
    const float* b2[3] = {(const float*)d_in[4], (const float*)d_in[6], (const float*)d_in[8]};
    const float* w3[3] = {(const float*)d_in[9], (const float*)d_in[11], (const float*)d_in[13]};
    const float* b3[3] = {(const float*)d_in[10], (const float*)d_in[12], (const float*)d_in[14]};
    const float* w4[3] = {(const float*)d_in[15], (const float*)d_in[17], (const float*)d_in[19]};
    const float* b4[3] = {(const float*)d_in[16], (const float*)d_in[18], (const float*)d_in[20]};

    float* out = (float*)d_out;

    float* ws_maxs = (float*)d_ws;                    // [16][8400]
    int* ws_cls = (int*)(ws_maxs + BS * A_TOT);       // [16][8400]
    int* ws_top = (int*)(ws_cls + BS * A_TOT);        // [16][100]

    // fused scores: 32 (L2) + 112 (L1) + 400 (L0) blocks of 256 threads
    scores_fused<<<dim3(544), 256, 0, stream>>>(
        x0, x1, x2, w3[0], w3[1], w3[2], b3[0], b3[1], b3[2], ws_maxs, ws_cls);
    topk_kernel<<<dim3(BS), 1024, 0, stream>>>(ws_maxs, ws_cls, out, ws_top);
    decode_kernel<<<dim3(MAX_DET, BS), 128, 0, stream>>>(
        x0, x1, x2,
        w2[0], b2[0], w2[1], b2[1], w2[2], b2[2],
        w4[0], b4[0], w4[1], b4[1], w4[2], b4[2],
        ws_top, out);
}

// Round 6
// 300.433 us; speedup vs baseline: 1.4453x; 1.4453x over previous
//
#include <hip/hip_runtime.h>
#include <hip/hip_bf16.h>

#define NC 80
#define NK 51
#define REG_MAX 16
#define MAX_DET 100
#define A_TOT 8400
#define BS 16

// out layout (float32): num[16] | boxes[16*100*4] | scores[16*100] | classes[16*100] | kpts[16*100*17*3]
#define OUT_NUM 0
#define OUT_BOX 16
#define OUT_SCORE (16 + 16*MAX_DET*4)
#define OUT_CLASS (OUT_SCORE + 16*MAX_DET)
#define OUT_KPT (OUT_CLASS + 16*MAX_DET)

static __device__ __forceinline__ unsigned long long mk_key(unsigned u, int a) {
    return ((unsigned long long)u << 32) | (unsigned)(0x7FFFFFFF - a);
}

// -------- Kernel 1: fused class scores (v1 structure — best measured, 102 us) --------
// Block: 256 threads = 4 waves (20 ocs each) x 64 lanes; 128 anchors/block
// (2 per thread). Weights staged in LDS per 32-channel chunk (broadcast
// ds_read_b128); features in LDS [c][a].
__global__ __launch_bounds__(256) void scores_fused(
    const float* __restrict__ x0, const float* __restrict__ x1, const float* __restrict__ x2,
    const float* __restrict__ w0, const float* __restrict__ w1, const float* __restrict__ w2,
    const float* __restrict__ bias0, const float* __restrict__ bias1, const float* __restrict__ bias2,
    float* __restrict__ max_s,       // [BS][A_TOT]
    int* __restrict__ cls_id)        // [BS][A_TOT]
{
    __shared__ float fs[32 * 128];   // 16 KB  [c][a]
    __shared__ float wsh[80 * 32];   // 10 KB  [oc][c]
    __shared__ float rm[4][128];
    __shared__ int   ri[4][128];

    int bid = blockIdx.x;
    const float *x, *w, *bias; int C, A, a_off, b, tile;
    if (bid < 64) {                 // level 2 first: longest serial work, overlap with rest
        x = x2; w = w2; bias = bias2; C = 512; A = 400; a_off = 8000;
        b = bid >> 2; tile = bid & 3;
    } else if (bid < 272) {         // level 1: 16 b x 13 tiles
        int r = bid - 64;
        x = x1; w = w1; bias = bias1; C = 256; A = 1600; a_off = 6400;
        b = r / 13; tile = r - b * 13;
    } else {                        // level 0: 16 b x 50 tiles
        int r = bid - 272;
        x = x0; w = w0; bias = bias0; C = 128; A = 6400; a_off = 0;
        b = r / 50; tile = r - b * 50;
    }
    int a0 = tile * 128;

    int t = threadIdx.x;
    int lane = t & 63;
    int wv = t >> 6;
    int oc0 = wv * 20;

    float acc0[20], acc1[20];
#pragma unroll
    for (int j = 0; j < 20; ++j) { float bv = bias[oc0 + j]; acc0[j] = bv; acc1[j] = bv; }

    const float* xb = x + (long)b * C * A;
    int nchunk = C >> 5;

    for (int kc = 0; kc < nchunk; ++kc) {
        __syncthreads();
        // stage features: 32 channels x 128 anchors (1024 float4)
#pragma unroll
        for (int i = 0; i < 4; ++i) {
            int idx = t + i * 256;
            int c = idx >> 5;
            int q = (idx & 31) * 4;
            int aa = a0 + q; if (aa > A - 4) aa = A - 4;
            float4 v = *(const float4*)(xb + (long)(kc * 32 + c) * A + aa);
            *(float4*)(&fs[c * 128 + q]) = v;
        }
        // stage weights: 80 ocs x 32 channels (640 float4)
#pragma unroll
        for (int i = 0; i < 3; ++i) {
            int idx = t + i * 256;
            if (idx < 640) {
                int oc = idx >> 3;
                int q = (idx & 7) * 4;
                float4 v = *(const float4*)(w + oc * C + kc * 32 + q);
                *(float4*)(&wsh[oc * 32 + q]) = v;
            }
        }
        __syncthreads();

#pragma unroll 1
        for (int c4 = 0; c4 < 32; c4 += 4) {
            float fa[4], fb[4];
#pragma unroll
            for (int cc = 0; cc < 4; ++cc) {
                fa[cc] = fs[(c4 + cc) * 128 + lane];
                fb[cc] = fs[(c4 + cc) * 128 + lane + 64];
            }
#pragma unroll
            for (int j = 0; j < 20; ++j) {
                float4 w4 = *(const float4*)(&wsh[(oc0 + j) * 32 + c4]);  // broadcast
                acc0[j] = fmaf(w4.x, fa[0], acc0[j]);
                acc0[j] = fmaf(w4.y, fa[1], acc0[j]);
                acc0[j] = fmaf(w4.z, fa[2], acc0[j]);
                acc0[j] = fmaf(w4.w, fa[3], acc0[j]);
                acc1[j] = fmaf(w4.x, fb[0], acc1[j]);
                acc1[j] = fmaf(w4.y, fb[1], acc1[j]);
                acc1[j] = fmaf(w4.z, fb[2], acc1[j]);
                acc1[j] = fmaf(w4.w, fb[3], acc1[j]);
            }
        }
    }

    // per-anchor argmax over this thread's 20 ocs (first-max semantics)
    float m0 = acc0[0], m1 = acc1[0]; int i0 = 0, i1 = 0;
#pragma unroll
    for (int j = 1; j < 20; ++j) {
        if (acc0[j] > m0) { m0 = acc0[j]; i0 = j; }
        if (acc1[j] > m1) { m1 = acc1[j]; i1 = j; }
    }
    i0 += oc0; i1 += oc0;

    rm[wv][lane] = m0;      ri[wv][lane] = i0;
    rm[wv][lane + 64] = m1; ri[wv][lane + 64] = i1;
    __syncthreads();
    if (wv == 0) {
#pragma unroll
        for (int p = 0; p < 2; ++p) {
            int a = lane + p * 64;
            float bm = rm[0][a]; int bi = ri[0][a];
#pragma unroll
            for (int v = 1; v < 4; ++v) {
                float om = rm[v][a];
                if (om > bm) { bm = om; bi = ri[v][a]; }  // ascending oc keeps first max
            }
            int ga = a0 + a;
            if (ga < A) {
                max_s[b * A_TOT + a_off + ga] = 1.0f / (1.0f + expf(-bm));
                cls_id[b * A_TOT + a_off + ga] = bi;
            }
        }
    }
}

// -------- Kernel 2 v2: exact top-100 radix select, 256 threads, barrier-light --------
// Old version: 1024 threads, ~80 sixteen-wave barriers per block (scan loop
// alone = 64) with ~100cy work between -> barrier-bound on 1 CU. New: 4
// waves; the 256-bin suffix scan lives entirely in wave 0 registers
// (shfl suffix-scan, zero barriers, no LDS scan array, no atomicMax);
// 3 barriers per radix pass. Selection semantics identical: exact
// top-100 by (score desc, anchor asc), same mk_key bitonic final sort.
__global__ __launch_bounds__(256) void topk_kernel(
    const float* __restrict__ max_s, // [BS][A_TOT]
    const int* __restrict__ cls_id,  // [BS][A_TOT]
    float* __restrict__ out,
    int* __restrict__ top_idx)       // [BS][MAX_DET]
{
    int b = blockIdx.x;
    int t = threadIdx.x;
    int lane = t & 63;
    int wv = t >> 6;

    __shared__ unsigned hist[4 * 256];           // 4 KB per-wave histograms
    __shared__ int tieIdx[A_TOT];                // 33.6 KB (worst-case ties)
    __shared__ unsigned long long highKeys[128];
    __shared__ unsigned long long finalKeys[128];
    __shared__ int wmin[4];
    __shared__ unsigned s_prefix;
    __shared__ int s_k, s_nHigh, s_nTie, s_cnt, s_bcast;

    // load: 8400 = 2100 uint4; thread t owns uint4 idx {t, t+256, ..., t+2048}
    // (i<8 always valid; i==8 valid iff t<52). anchor a = idx*4 + j.
    uint4 uu[9];
#pragma unroll
    for (int i = 0; i < 9; ++i) {
        int idx = t + i * 256;
        if (i < 8 || t < 52)
            uu[i] = *(const uint4*)((const unsigned*)(max_s + (long)b * A_TOT) + idx * 4);
        else
            uu[i] = make_uint4(0u, 0u, 0u, 0u);
    }

    if (t == 0) { s_prefix = 0; s_k = MAX_DET; s_nHigh = 0; s_nTie = 0; s_cnt = 0; }

    for (int pass = 0; pass < 4; ++pass) {
#pragma unroll
        for (int j = 0; j < 4; ++j) hist[t + j * 256] = 0;
        __syncthreads();                         // A: zeroed (also covers init / prev update)

        unsigned pre = s_prefix;
        int k = s_k;
        int shHi = 32 - 8 * pass;
        int shD = 24 - 8 * pass;
#pragma unroll
        for (int i = 0; i < 9; ++i) {
            if (i < 8 || t < 52) {
                unsigned e[4] = { uu[i].x, uu[i].y, uu[i].z, uu[i].w };
#pragma unroll
                for (int j = 0; j < 4; ++j) {
                    bool cand = (pass == 0) ? true : ((e[j] >> shHi) == pre);
                    if (cand)
                        atomicAdd(&hist[(wv << 8) + ((e[j] >> shD) & 0xFF)], 1u);
                }
            }
        }
        __syncthreads();                         // B: histograms complete

        if (wv == 0) {
            // lane owns bins 4*lane .. 4*lane+3; sum across the 4 wave-copies
            unsigned c0 = 0, c1 = 0, c2 = 0, c3 = 0;
#pragma unroll
            for (int w = 0; w < 4; ++w) {
                const unsigned* hp = &hist[(w << 8) + lane * 4];
                c0 += hp[0]; c1 += hp[1]; c2 += hp[2]; c3 += hp[3];
            }
            // in-register suffix within the lane's 4 bins
            unsigned s3 = c3, s2 = c2 + s3, s1 = c1 + s2, s0 = c0 + s1;
            // cross-lane suffix of lane totals (Hillis-Steele, shfl only)
            unsigned tsum = s0;
#pragma unroll
            for (int off = 1; off < 64; off <<= 1) {
                unsigned o = __shfl_down(tsum, off, 64);
                if (lane + off < 64) tsum += o;
            }
            unsigned excl = tsum - s0;           // sum over lanes > lane
            unsigned S0 = excl + s0, S1 = excl + s1, S2 = excl + s2, S3 = excl + s3;
            // selD = max d with suffix(d) >= k  (S non-increasing in d)
            int ld = -1;
            unsigned uk = (unsigned)k;
            if (S3 >= uk)      ld = lane * 4 + 3;
            else if (S2 >= uk) ld = lane * 4 + 2;
            else if (S1 >= uk) ld = lane * 4 + 1;
            else if (S0 >= uk) ld = lane * 4 + 0;
            int d = ld;
#pragma unroll
            for (int off = 32; off > 0; off >>= 1) d = max(d, __shfl_xor(d, off, 64));
            // suffix(d+1): owned by lane (d+1)>>2 (0 if d==255); sum-broadcast
            int dn = d + 1;
            unsigned mine = 0;
            if (dn < 256 && lane == (dn >> 2)) {
                int e = dn & 3;
                mine = (e == 0) ? S0 : (e == 1) ? S1 : (e == 2) ? S2 : S3;
            }
#pragma unroll
            for (int off = 32; off > 0; off >>= 1) mine += __shfl_xor(mine, off, 64);
            if (lane == 0) {
                s_k = k - (int)mine;
                s_prefix = (pre << 8) | (unsigned)d;
            }
        }
        __syncthreads();                         // C: cut update visible
    }

    unsigned cut = s_prefix;
    int r = s_k;

#pragma unroll
    for (int i = 0; i < 9; ++i) {
        if (i < 8 || t < 52) {
            unsigned e[4] = { uu[i].x, uu[i].y, uu[i].z, uu[i].w };
#pragma unroll
            for (int j = 0; j < 4; ++j) {
                int a = (t + i * 256) * 4 + j;
                if (e[j] > cut) {
                    int p = atomicAdd(&s_nHigh, 1);
                    highKeys[p] = mk_key(e[j], a);
                } else if (e[j] == cut) {
                    int p = atomicAdd(&s_nTie, 1);
                    tieIdx[p] = a;
                }
            }
        }
    }
    __syncthreads();
    int m = s_nHigh;
    int nt = s_nTie;

    if (t < 128) finalKeys[t] = 0ull;
    __syncthreads();
    if (t < m) finalKeys[t] = highKeys[t];

    if (nt == r) {
        if (t < nt) finalKeys[m + t] = mk_key(cut, tieIdx[t]);
        __syncthreads();
    } else {
        __syncthreads();
        for (int j = 0; j < r; ++j) {
            int mn = 0x7FFFFFFF;
            for (int p = t; p < nt; p += 256) mn = min(mn, tieIdx[p]);
            for (int off = 32; off > 0; off >>= 1) mn = min(mn, __shfl_down(mn, off, 64));
            if (lane == 0) wmin[wv] = mn;
            __syncthreads();
            if (t == 0) {
                int v = min(min(wmin[0], wmin[1]), min(wmin[2], wmin[3]));
                s_bcast = v;
                finalKeys[m + j] = mk_key(cut, v);
            }
            __syncthreads();
            int v = s_bcast;
            for (int p = t; p < nt; p += 256)
                if (tieIdx[p] == v) tieIdx[p] = 0x7FFFFFFF;
            __syncthreads();
        }
    }

    for (int ksz = 2; ksz <= 128; ksz <<= 1) {
        for (int j = ksz >> 1; j > 0; j >>= 1) {
            if (t < 128) {
                int ixj = t ^ j;
                if (ixj > t) {
                    bool desc = ((t & ksz) == 0);
                    unsigned long long x = finalKeys[t], y = finalKeys[ixj];
                    bool sw = desc ? (x < y) : (x > y);
                    if (sw) { finalKeys[t] = y; finalKeys[ixj] = x; }
                }
            }
            __syncthreads();
        }
    }

    if (t < MAX_DET) {
        unsigned long long kk = finalKeys[t];
        float sc = __uint_as_float((unsigned)(kk >> 32));
        int a = 0x7FFFFFFF - (int)(kk & 0xFFFFFFFFull);
        out[OUT_SCORE + b * MAX_DET + t] = sc;
        out[OUT_CLASS + b * MAX_DET + t] = (float)cls_id[b * A_TOT + a];
        top_idx[b * MAX_DET + t] = a;
        if (sc > 0.25f) atomicAdd(&s_cnt, 1);
    }
    __syncthreads();
    if (t == 0) out[OUT_NUM + b] = (float)s_cnt;
}

// -------- Kernel 3: decode box + kpts for selected anchors (float4 dot) --------
__global__ __launch_bounds__(128) void decode_kernel(
    const float* __restrict__ x0, const float* __restrict__ x1, const float* __restrict__ x2,
    const float* __restrict__ w2_0, const float* __restrict__ b2_0,
    const float* __restrict__ w2_1, const float* __restrict__ b2_1,
    const float* __restrict__ w2_2, const float* __restrict__ b2_2,
    const float* __restrict__ w4_0, const float* __restrict__ b4_0,
    const float* __restrict__ w4_1, const float* __restrict__ b4_1,
    const float* __restrict__ w4_2, const float* __restrict__ b4_2,
    const int* __restrict__ top_idx,
    float* __restrict__ out)
{
    int b = blockIdx.y;
    int k = blockIdx.x;
    int a = top_idx[b * MAX_DET + k];

    const float* x; const float* w2; const float* bb2; const float* w4; const float* bb4;
    int C, A, W, a_local; float stride;
    if (a < 6400)      { x = x0; C = 128; A = 6400; W = 80; stride = 8.0f;  a_local = a;        w2 = w2_0; bb2 = b2_0; w4 = w4_0; bb4 = b4_0; }
    else if (a < 8000) { x = x1; C = 256; A = 1600; W = 40; stride = 16.0f; a_local = a - 6400; w2 = w2_1; bb2 = b2_1; w4 = w4_1; bb4 = b4_1; }
    else               { x = x2; C = 512; A = 400;  W = 20; stride = 32.0f; a_local = a - 8000; w2 = w2_2; bb2 = b2_2; w4 = w4_2; bb4 = b4_2; }

    __shared__ float fs[512];
    __shared__ float logits[64];
    __shared__ float kraw[NK];
    __shared__ float dist[4];

    int t = threadIdx.x;
    for (int c = t; c < C; c += 128)
        fs[c] = x[((long)b * C + c) * A + a_local];
    __syncthreads();

    if (t < 64 + NK) {
        const float* wrow; float acc;
        if (t < 64) { wrow = w2 + t * C; acc = bb2[t]; }
        else        { wrow = w4 + (t - 64) * C; acc = bb4[t - 64]; }
        // float4 both sides, ascending-c fmaf order -> bit-identical
        for (int c = 0; c < C; c += 4) {
            float4 wv4 = *(const float4*)(wrow + c);
            float4 fv4 = *(const float4*)(&fs[c]);
            acc = fmaf(wv4.x, fv4.x, acc);
            acc = fmaf(wv4.y, fv4.y, acc);
            acc = fmaf(wv4.z, fv4.z, acc);
            acc = fmaf(wv4.w, fv4.w, acc);
        }
        if (t < 64) logits[t] = acc;
        else        kraw[t - 64] = acc;
    }
    __syncthreads();

    if (t < 4) {
        float mx = logits[t * 16];
#pragma unroll
        for (int r = 1; r < 16; ++r) mx = fmaxf(mx, logits[t * 16 + r]);
        float se = 0.0f, sw = 0.0f;
#pragma unroll
        for (int r = 0; r < 16; ++r) {
            float e = expf(logits[t * 16 + r] - mx);
            se += e; sw += e * (float)r;
        }
        dist[t] = sw / se;
    }
    __syncthreads();

    float ax = (float)(a_local % W) + 0.5f;
    float ay = (float)(a_local / W) + 0.5f;

    if (t == 0) {
        float x1c = ax - dist[0], y1c = ay - dist[1];
        float x2c = ax + dist[2], y2c = ay + dist[3];
        float* ob = out + OUT_BOX + ((long)b * MAX_DET + k) * 4;
        ob[0] = (x1c + x2c) * 0.5f * stride;
        ob[1] = (y1c + y2c) * 0.5f * stride;
        ob[2] = (x2c - x1c) * stride;
        ob[3] = (y2c - y1c) * stride;
    }
    if (t < 17) {
        float vx = kraw[t * 3], vy = kraw[t * 3 + 1], vv = kraw[t * 3 + 2];
        float gx = ax - 0.5f, gy = ay - 0.5f;
        float* ok = out + OUT_KPT + (((long)b * MAX_DET + k) * 17 + t) * 3;
        ok[0] = (vx * 2.0f + gx) * stride;
        ok[1] = (vy * 2.0f + gy) * stride;
        ok[2] = 1.0f / (1.0f + expf(-vv));
    }
}

extern "C" void kernel_launch(void* const* d_in, const int* in_sizes, int n_in,
                              void* d_out, int out_size, void* d_ws, size_t ws_size,
                              hipStream_t stream) {
    const float* x0 = (const float*)d_in[0];
    const float* x1 = (const float*)d_in[1];
    const float* x2 = (const float*)d_in[2];
    const float* w2[3] = {(const float*)d_in[3], (const float*)d_in[5], (const float*)d_in[7]};
    const float* b2[3] = {(const float*)d_in[4], (const float*)d_in[6], (const float*)d_in[8]};
    const float* w3[3] = {(const float*)d_in[9], (const float*)d_in[11], (const float*)d_in[13]};
    const float* b3[3] = {(const float*)d_in[10], (const float*)d_in[12], (const float*)d_in[14]};
    const float* w4[3] = {(const float*)d_in[15], (const float*)d_in[17], (const float*)d_in[19]};
    const float* b4[3] = {(const float*)d_in[16], (const float*)d_in[18], (const float*)d_in[20]};

    float* out = (float*)d_out;

    float* ws_maxs = (float*)d_ws;                    // [16][8400]
    int* ws_cls = (int*)(ws_maxs + BS * A_TOT);       // [16][8400]
    int* ws_top = (int*)(ws_cls + BS * A_TOT);        // [16][100]

    // fused scores: 64 (L2) + 208 (L1) + 800 (L0) blocks
    scores_fused<<<dim3(1072), 256, 0, stream>>>(
        x0, x1, x2, w3[0], w3[1], w3[2], b3[0], b3[1], b3[2], ws_maxs, ws_cls);
    topk_kernel<<<dim3(BS), 256, 0, stream>>>(ws_maxs, ws_cls, out, ws_top);
    decode_kernel<<<dim3(MAX_DET, BS), 128, 0, stream>>>(
        x0, x1, x2,
        w2[0], b2[0], w2[1], b2[1], w2[2], b2[2],
        w4[0], b4[0], w4[1], b4[1], w4[2], b4[2],
        ws_top, out);
}